// Round 11
// baseline (1041.307 us; speedup 1.0000x reference)
//
#include <hip/hip_runtime.h>
#include <hip/hip_bf16.h>
#include <math.h>

// Problem constants
#define BB   4
#define SSQ  1024
#define DDM  512
#define HHD  8
#define KTOP 204
#define NPAT 8
#define PDIM 64

typedef unsigned long long u64;
typedef unsigned int u32;
typedef unsigned short u16;

// Polymorphic input loader: flag==1 -> f32 data, flag==0 -> bf16 data.
__device__ __forceinline__ float ldin(const void* p, size_t i, int f32) {
    if (f32) return ((const float*)p)[i];
    u16 h = ((const u16*)p)[i];
    return __uint_as_float(((u32)h) << 16);
}

// ---------------------------------------------------------------------------
// K0: input dtype detection (validated decision rule).
// ---------------------------------------------------------------------------
__global__ __launch_bounds__(64)
void detect_kernel(const void* q, int* flag) {
    int lane = threadIdx.x;
    const u16* p = (const u16*)q;
    int good = 0;
    #pragma unroll
    for (int k = 0; k < 4; ++k) {
        int i = (lane * 4 + k) * 2;
        float v = __uint_as_float(((u32)p[i]) << 16);
        float a = fabsf(v);
        if (a > 0.00390625f && a < 64.f) ++good;
    }
    #pragma unroll
    for (int off = 32; off >= 1; off >>= 1) good += __shfl_xor(good, off);
    if (lane == 0) *flag = (good < 128) ? 1 : 0;
}

// ---------------------------------------------------------------------------
// K1: pattern learner -> weighted_patterns (out2, f32). One block per row.
// ---------------------------------------------------------------------------
__global__ __launch_bounds__(64)
void pattern_kernel(const void* __restrict__ q,
                    const void* __restrict__ pw1, const void* __restrict__ pb1,
                    const void* __restrict__ pw2, const void* __restrict__ pb2,
                    const void* __restrict__ bank, const void* __restrict__ gate,
                    const int* __restrict__ flagp,
                    float* __restrict__ out2) {
    __shared__ float qs[DDM];
    __shared__ float h1[PDIM];
    __shared__ float enc[PDIM];
    __shared__ float ps[NPAT];
    int f32 = *flagp;
    int row = blockIdx.x;
    int t = threadIdx.x;
    for (int i = t; i < DDM; i += 64) qs[i] = ldin(q, (size_t)row * DDM + i, f32);
    __syncthreads();
    float a0 = ldin(pb1, t, f32), a1 = 0.f, a2 = 0.f, a3 = 0.f;
    #pragma unroll 4
    for (int d = 0; d < DDM; d += 4) {
        a0 = fmaf(qs[d + 0], ldin(pw1, (size_t)(d + 0) * PDIM + t, f32), a0);
        a1 = fmaf(qs[d + 1], ldin(pw1, (size_t)(d + 1) * PDIM + t, f32), a1);
        a2 = fmaf(qs[d + 2], ldin(pw1, (size_t)(d + 2) * PDIM + t, f32), a2);
        a3 = fmaf(qs[d + 3], ldin(pw1, (size_t)(d + 3) * PDIM + t, f32), a3);
    }
    h1[t] = fmaxf((a0 + a1) + (a2 + a3), 0.f);
    __syncthreads();
    float acc2 = ldin(pb2, t, f32);
    for (int d = 0; d < PDIM; ++d) acc2 = fmaf(h1[d], ldin(pw2, (size_t)d * PDIM + t, f32), acc2);
    enc[t] = tanhf(acc2);
    __syncthreads();
    if (t < NPAT) {
        float a = 0.f;
        for (int d = 0; d < PDIM; ++d) a = fmaf(enc[d], ldin(bank, (size_t)t * PDIM + d, f32), a);
        ps[t] = a * 0.125f;
    }
    __syncthreads();
    if (t < NPAT) {
        float m = ps[0];
        for (int n = 1; n < NPAT; ++n) m = fmaxf(m, ps[n]);
        float sum = 0.f;
        for (int n = 0; n < NPAT; ++n) sum += expf(ps[n] - m);
        float e = expf(ps[t] - m);
        out2[(size_t)row * NPAT + t] = e / sum * ldin(gate, t, f32);
    }
}

// ---------------------------------------------------------------------------
// K2: f32 projection (z=0:Q, 1:K, 2:V). EXACT-SENSITIVE — per-element
// sequential FMA chain over d ascending (validated rounds 8-10). Unchanged.
// ---------------------------------------------------------------------------
__global__ __launch_bounds__(256)
void projf_kernel(const void* __restrict__ query, const void* __restrict__ key,
                  const void* __restrict__ value,
                  const void* __restrict__ wq, const void* __restrict__ bq,
                  const void* __restrict__ wk, const void* __restrict__ bk,
                  const void* __restrict__ wv, const void* __restrict__ bv,
                  const int* __restrict__ flagp,
                  float* __restrict__ Qf32, float* __restrict__ Kf32, float* __restrict__ Vf32) {
    __shared__ float Xs[64][68];
    __shared__ float Ws[64][68];
    int f32 = *flagp;
    int z = blockIdx.z;
    const void* X = (z == 0) ? query : ((z == 1) ? key : value);
    const void* W = (z == 0) ? wq : ((z == 1) ? wk : wv);
    const void* Bv = (z == 0) ? bq : ((z == 1) ? bk : bv);
    float* Y = (z == 0) ? Qf32 : ((z == 1) ? Kf32 : Vf32);
    int c0 = blockIdx.x * 64, r0 = blockIdx.y * 64;
    int tx = threadIdx.x & 15, ty = threadIdx.x >> 4;
    float acc[4][4] = {};
    for (int k0 = 0; k0 < DDM; k0 += 64) {
        for (int idx = threadIdx.x; idx < 64 * 64; idx += 256) {
            int r = idx >> 6, kk = idx & 63;
            Xs[r][kk] = ldin(X, (size_t)(r0 + r) * DDM + k0 + kk, f32);
            Ws[r][kk] = ldin(W, (size_t)(k0 + r) * DDM + c0 + kk, f32);
        }
        __syncthreads();
        #pragma unroll 4
        for (int kk = 0; kk < 64; kk += 4) {
            float4 xv[4];
            #pragma unroll
            for (int a = 0; a < 4; ++a)
                xv[a] = *reinterpret_cast<const float4*>(&Xs[ty + 16 * a][kk]);
            #pragma unroll
            for (int j = 0; j < 4; ++j) {          // sub-k ascending: exact chain
                float4 wv = *reinterpret_cast<const float4*>(&Ws[kk + j][4 * tx]);
                #pragma unroll
                for (int a = 0; a < 4; ++a) {
                    float x = ((const float*)&xv[a])[j];
                    acc[a][0] = fmaf(x, wv.x, acc[a][0]);
                    acc[a][1] = fmaf(x, wv.y, acc[a][1]);
                    acc[a][2] = fmaf(x, wv.z, acc[a][2]);
                    acc[a][3] = fmaf(x, wv.w, acc[a][3]);
                }
            }
        }
        __syncthreads();
    }
    #pragma unroll
    for (int a = 0; a < 4; ++a) {
        int r = r0 + ty + 16 * a;
        float4 o;
        o.x = acc[a][0] + ldin(Bv, c0 + 4 * tx + 0, f32);
        o.y = acc[a][1] + ldin(Bv, c0 + 4 * tx + 1, f32);
        o.z = acc[a][2] + ldin(Bv, c0 + 4 * tx + 2, f32);
        o.w = acc[a][3] + ldin(Bv, c0 + 4 * tx + 3, f32);
        *reinterpret_cast<float4*>(&Y[(size_t)r * DDM + c0 + 4 * tx]) = o;
    }
}

// ---------------------------------------------------------------------------
// K3: f32 scores, all batches. EXACT-SENSITIVE — unchanged from round 10.
// ---------------------------------------------------------------------------
__global__ __launch_bounds__(256)
void scoresf_kernel(const float* __restrict__ Qf32, const float* __restrict__ Kf32,
                    float* __restrict__ S3f) {
    __shared__ float Qs[64][68];
    __shared__ float Ks[64][68];
    int b = blockIdx.z;
    const float* Qb = Qf32 + (size_t)b * SSQ * DDM;
    const float* Kb = Kf32 + (size_t)b * SSQ * DDM;
    float* S3 = S3f + (size_t)b * SSQ * SSQ;
    int j0 = blockIdx.x * 64, i0 = blockIdx.y * 64;
    int tx = threadIdx.x & 15, ty = threadIdx.x >> 4;
    float acc[4][4] = {};
    for (int k0 = 0; k0 < DDM; k0 += 64) {
        for (int idx = threadIdx.x; idx < 64 * 64; idx += 256) {
            int r = idx >> 6, kk = idx & 63;
            Qs[r][kk] = Qb[(size_t)(i0 + r) * DDM + k0 + kk];
            Ks[r][kk] = Kb[(size_t)(j0 + r) * DDM + k0 + kk];
        }
        __syncthreads();
        #pragma unroll 4
        for (int kk = 0; kk < 64; kk += 4) {
            float4 qv[4], kv[4];
            #pragma unroll
            for (int a = 0; a < 4; ++a)
                qv[a] = *reinterpret_cast<const float4*>(&Qs[ty + 16 * a][kk]);
            #pragma unroll
            for (int b2 = 0; b2 < 4; ++b2)
                kv[b2] = *reinterpret_cast<const float4*>(&Ks[tx + 16 * b2][kk]);
            #pragma unroll
            for (int a = 0; a < 4; ++a)
                #pragma unroll
                for (int b2 = 0; b2 < 4; ++b2) {   // .x,.y,.z,.w ascending: exact
                    acc[a][b2] = fmaf(qv[a].x, kv[b2].x, acc[a][b2]);
                    acc[a][b2] = fmaf(qv[a].y, kv[b2].y, acc[a][b2]);
                    acc[a][b2] = fmaf(qv[a].z, kv[b2].z, acc[a][b2]);
                    acc[a][b2] = fmaf(qv[a].w, kv[b2].w, acc[a][b2]);
                }
        }
        __syncthreads();
    }
    #pragma unroll
    for (int a = 0; a < 4; ++a)
        #pragma unroll
        for (int b2 = 0; b2 < 4; ++b2)
            S3[(size_t)(i0 + ty + 16 * a) * SSQ + (j0 + tx + 16 * b2)] = acc[a][b2] * 0.125f;
}

// ---------------------------------------------------------------------------
// K4: per-row top-204 via 4-pass radix select (integer-exact, same tie
// semantics as validated round 9). Scans rewritten with wave shuffles +
// one cross-wave LDS combine (3 barriers/pass instead of 17).
// ---------------------------------------------------------------------------
__global__ __launch_bounds__(256)
void maskselect_kernel(const float* __restrict__ S3f,
                       u64* __restrict__ bitmask) {   // (B*S, 16)
    __shared__ u32 keys[1024];
    __shared__ u32 sel[1024];
    __shared__ u32 hist[256];
    __shared__ u32 wtot[4];
    __shared__ u32 pick_digit, pick_rem;
    int i = blockIdx.x, b = blockIdx.y;
    int t = threadIdx.x;
    int lane = t & 63, w = t >> 6;
    const float* srow = S3f + (size_t)b * SSQ * SSQ + (size_t)i * SSQ;
    for (int j = t; j < 1024; j += 256) {
        u32 bits = __float_as_uint(srow[j]);
        keys[j] = (bits & 0x80000000u) ? ~bits : (bits | 0x80000000u);
    }
    __syncthreads();
    u32 prefix = 0, himask = 0, rem = KTOP;
    for (int p = 3; p >= 0; --p) {
        int shift = p * 8;
        hist[t] = 0;
        __syncthreads();
        for (int j = t; j < 1024; j += 256) {
            u32 kb = keys[j];
            if ((kb & himask) == prefix) atomicAdd(&hist[(kb >> shift) & 0xFFu], 1u);
        }
        __syncthreads();
        // suffix sum over hist via wave shuffles (integer-exact)
        u32 hv = hist[t];
        u32 sfx = hv;
        #pragma unroll
        for (int off = 1; off < 64; off <<= 1) {
            u32 o = __shfl_down(sfx, off);
            if (lane + off < 64) sfx += o;
        }
        if (lane == 0) wtot[w] = sfx;          // segment totals
        __syncthreads();
        u32 add = 0;
        for (int q = w + 1; q < 4; ++q) add += wtot[q];
        u32 ssum_t = sfx + add;                 // suffix incl. t
        u32 nxt = ssum_t - hv;                  // suffix excl. t
        if (ssum_t >= rem && nxt < rem) { pick_digit = (u32)t; pick_rem = rem - nxt; }
        __syncthreads();
        prefix |= pick_digit << shift;
        rem = pick_rem;
        himask |= (0xFFu << shift);
        __syncthreads();
    }
    u32 vstar = prefix;
    u32 tneed = rem;                 // how many == vstar to take, ascending index
    u32 eq[4]; u32 local = 0;
    #pragma unroll
    for (int a = 0; a < 4; ++a) {
        int j = 4 * t + a;
        u32 kb = keys[j];
        sel[j] = (kb > vstar) ? 1u : 0u;
        eq[a] = (kb == vstar) ? 1u : 0u;
        local += eq[a];
    }
    // inclusive prefix scan of `local` via wave shuffles + cross-wave combine
    u32 pre = local;
    #pragma unroll
    for (int off = 1; off < 64; off <<= 1) {
        u32 o = __shfl_up(pre, off);
        if (lane >= off) pre += o;
    }
    if (lane == 63) wtot[w] = pre;
    __syncthreads();
    u32 addp = 0;
    for (int q = 0; q < w; ++q) addp += wtot[q];
    u32 base = pre + addp - local;              // exclusive rank among equals
    #pragma unroll
    for (int a = 0; a < 4; ++a) {
        if (eq[a]) { if (base < tneed) sel[4 * t + a] = 1u; base += 1; }
    }
    __syncthreads();
    if (t < 16) {
        u64 wbits = 0;
        for (int l = 0; l < 64; ++l)
            if (sel[t * 64 + l]) wbits |= (1ull << l);
        bitmask[((size_t)b * SSQ + i) * 16 + t] = wbits;
    }
}

// ---------------------------------------------------------------------------
// K5: sparse attention — one BLOCK (4 waves) per (b,h,i) row.
// Scores: one column per thread (2-partial chain, low VGPR). V-accum: 204
// entries split across 4 waves (~51 each, 4 chains) + LDS reduction.
// Loose-tolerance path. Occupancy (TLP) is the latency hider here — keep
// VGPR low (round-10 lesson: ILP unroll cost 88%->45% occupancy, net loss).
// ---------------------------------------------------------------------------
__global__ __launch_bounds__(256)
void attn_sparse_kernel(const float* __restrict__ Qf32, const float* __restrict__ Kf32,
                        const float* __restrict__ Vf32, const u64* __restrict__ bitmask,
                        float* __restrict__ AO) {
    __shared__ float qs[64];
    __shared__ float pbuf[256];
    __shared__ u16 list[256];
    __shared__ float redm[4];
    __shared__ float redl[4];
    __shared__ float vred[4][64];
    __shared__ int cnt_s;
    int t = threadIdx.x;
    int lane = t & 63, w = t >> 6;
    int i = blockIdx.x, h = blockIdx.y, b = blockIdx.z;
    size_t qoff = ((size_t)(b * SSQ + i)) * DDM + h * 64;
    if (t < 64) qs[t] = Qf32[qoff + t];
    if (w == 0) {
        const u64* mb = bitmask + ((size_t)(b * SSQ + i)) * 16;
        u64 below = (lane == 0) ? 0ull : (0xFFFFFFFFFFFFFFFFull >> (64 - lane));
        int cnt = 0;
        #pragma unroll
        for (int wd = 0; wd < 16; ++wd) {
            u64 word = mb[wd];                   // wave-uniform
            if ((word >> lane) & 1ull) {
                int pos = cnt + (int)__popcll(word & below);
                if (pos < 256) list[pos] = (u16)(wd * 64 + lane);
            }
            cnt += (int)__popcll(word);
        }
        if (lane == 0) cnt_s = (cnt > 256) ? 256 : cnt;
    }
    __syncthreads();
    int cnt = cnt_s;
    // one score per thread
    float s = -1e30f;
    if (t < cnt) {
        const float* kr = Kf32 + ((size_t)(b * SSQ + list[t])) * DDM + h * 64;
        const float4* q4 = reinterpret_cast<const float4*>(qs);
        const float4* k4 = reinterpret_cast<const float4*>(kr);
        float p0 = 0.f, p1 = 0.f;
        #pragma unroll
        for (int d4 = 0; d4 < 16; d4 += 2) {
            float4 qa = q4[d4], ka = k4[d4];
            float4 qb = q4[d4 + 1], kb = k4[d4 + 1];
            p0 = fmaf(qa.w, ka.w, fmaf(qa.z, ka.z, fmaf(qa.y, ka.y, fmaf(qa.x, ka.x, p0))));
            p1 = fmaf(qb.w, kb.w, fmaf(qb.z, kb.z, fmaf(qb.y, kb.y, fmaf(qb.x, kb.x, p1))));
        }
        s = (p0 + p1) * 0.125f;
    }
    // block max
    float m = s;
    #pragma unroll
    for (int off = 32; off >= 1; off >>= 1) m = fmaxf(m, __shfl_xor(m, off));
    if (lane == 0) redm[w] = m;
    __syncthreads();
    m = fmaxf(fmaxf(redm[0], redm[1]), fmaxf(redm[2], redm[3]));
    float p = (t < cnt) ? expf(s - m) : 0.f;
    pbuf[t] = p;
    float l = p;
    #pragma unroll
    for (int off = 32; off >= 1; off >>= 1) l += __shfl_xor(l, off);
    if (lane == 0) redl[w] = l;
    __syncthreads();
    float lsum = (redl[0] + redl[1]) + (redl[2] + redl[3]);
    // V accumulation: wave w takes a contiguous chunk of the list
    const float* Vb = Vf32 + (size_t)b * SSQ * DDM + h * 64 + lane;
    int chunk = (cnt + 3) >> 2;
    int lo = w * chunk;
    int hi = lo + chunk; if (hi > cnt) hi = cnt;
    float a0 = 0.f, a1 = 0.f, a2 = 0.f, a3 = 0.f;
    int tt = lo;
    for (; tt + 4 <= hi; tt += 4) {
        a0 = fmaf(pbuf[tt + 0], Vb[(size_t)list[tt + 0] * DDM], a0);
        a1 = fmaf(pbuf[tt + 1], Vb[(size_t)list[tt + 1] * DDM], a1);
        a2 = fmaf(pbuf[tt + 2], Vb[(size_t)list[tt + 2] * DDM], a2);
        a3 = fmaf(pbuf[tt + 3], Vb[(size_t)list[tt + 3] * DDM], a3);
    }
    for (; tt < hi; ++tt) a0 = fmaf(pbuf[tt], Vb[(size_t)list[tt] * DDM], a0);
    vred[w][lane] = ((a0 + a1) + (a2 + a3));
    __syncthreads();
    if (w == 0) {
        float acc = (vred[0][lane] + vred[1][lane]) + (vred[2][lane] + vred[3][lane]);
        AO[qoff + lane] = acc / lsum;
    }
}

// ---------------------------------------------------------------------------
// K6: output projection  out0 = AO @ wo + bo  (f32 out, loose tolerance)
// ---------------------------------------------------------------------------
__global__ __launch_bounds__(256)
void outproj_kernel(const float* __restrict__ AO, const void* __restrict__ wo,
                    const void* __restrict__ bo, const int* __restrict__ flagp,
                    float* __restrict__ out0) {
    __shared__ float Xs[64][68];
    __shared__ float Ws[64][68];
    int f32 = *flagp;
    int c0 = blockIdx.x * 64, r0 = blockIdx.y * 64;
    int tx = threadIdx.x & 15, ty = threadIdx.x >> 4;
    float acc[4][4] = {};
    for (int k0 = 0; k0 < DDM; k0 += 64) {
        for (int idx = threadIdx.x; idx < 64 * 64; idx += 256) {
            int r = idx >> 6, kk = idx & 63;
            Xs[r][kk] = AO[(size_t)(r0 + r) * DDM + k0 + kk];
            Ws[r][kk] = ldin(wo, (size_t)(k0 + r) * DDM + c0 + kk, f32);
        }
        __syncthreads();
        #pragma unroll 4
        for (int kk = 0; kk < 64; kk += 4) {
            float4 xv[4];
            #pragma unroll
            for (int a = 0; a < 4; ++a)
                xv[a] = *reinterpret_cast<const float4*>(&Xs[ty + 16 * a][kk]);
            #pragma unroll
            for (int j = 0; j < 4; ++j) {
                float4 wv = *reinterpret_cast<const float4*>(&Ws[kk + j][4 * tx]);
                #pragma unroll
                for (int a = 0; a < 4; ++a) {
                    float x = ((const float*)&xv[a])[j];
                    acc[a][0] = fmaf(x, wv.x, acc[a][0]);
                    acc[a][1] = fmaf(x, wv.y, acc[a][1]);
                    acc[a][2] = fmaf(x, wv.z, acc[a][2]);
                    acc[a][3] = fmaf(x, wv.w, acc[a][3]);
                }
            }
        }
        __syncthreads();
    }
    #pragma unroll
    for (int a = 0; a < 4; ++a) {
        int r = r0 + ty + 16 * a;
        float4 o;
        o.x = acc[a][0] + ldin(bo, c0 + 4 * tx + 0, f32);
        o.y = acc[a][1] + ldin(bo, c0 + 4 * tx + 1, f32);
        o.z = acc[a][2] + ldin(bo, c0 + 4 * tx + 2, f32);
        o.w = acc[a][3] + ldin(bo, c0 + 4 * tx + 3, f32);
        *reinterpret_cast<float4*>(&out0[(size_t)r * DDM + c0 + 4 * tx]) = o;
    }
}

// ---------------------------------------------------------------------------
// K7 (last): expand bitmask -> f32 mask for all 8 heads, overwriting ALL of
// out1 (which served as scratch until now). One block per (b,i) row.
// ---------------------------------------------------------------------------
__global__ __launch_bounds__(256)
void maskwrite_kernel(const u64* __restrict__ bitmask,
                      float* __restrict__ out1) {
    int row = blockIdx.x;            // b*S + i
    int t = threadIdx.x;
    int b = row >> 10, i = row & 1023;
    const u64* mb = bitmask + (size_t)row * 16;
    int j0 = t * 4;
    u64 w0 = mb[j0 >> 6];
    float4 v4;
    v4.x = ((w0 >> (j0 & 63)) & 1ull) ? 1.0f : 0.0f;
    v4.y = ((w0 >> ((j0 + 1) & 63)) & 1ull) ? 1.0f : 0.0f;
    v4.z = ((w0 >> ((j0 + 2) & 63)) & 1ull) ? 1.0f : 0.0f;
    v4.w = ((w0 >> ((j0 + 3) & 63)) & 1ull) ? 1.0f : 0.0f;
    for (int h = 0; h < HHD; ++h) {
        size_t base_o = (((size_t)b * HHD + h) * SSQ + i) * SSQ;
        *reinterpret_cast<float4*>(out1 + base_o + (size_t)t * 4) = v4;
    }
}

// ---------------------------------------------------------------------------
extern "C" void kernel_launch(void* const* d_in, const int* in_sizes, int n_in,
                              void* d_out, int out_size, void* d_ws, size_t ws_size,
                              hipStream_t stream) {
    const void* query = d_in[0];
    const void* key   = d_in[1];
    const void* value = d_in[2];
    const void* wq = d_in[3];  const void* bq = d_in[4];
    const void* wk = d_in[5];  const void* bk = d_in[6];
    const void* wv = d_in[7];  const void* bv = d_in[8];
    const void* wo = d_in[9];  const void* bo = d_in[10];
    const void* pw1 = d_in[11]; const void* pb1 = d_in[12];
    const void* pw2 = d_in[13]; const void* pb2 = d_in[14];
    const void* pattern_bank = d_in[15];
    const void* pattern_gate = d_in[16];

    // Outputs are FLOAT32 (validated round 8).
    float* out0 = (float*)d_out;                          // (B,S,D)   2M f32
    float* out1 = out0 + (size_t)BB * SSQ * DDM;          // (B,H,S,S) 33.5M f32 (134MB)
    float* out2 = out1 + (size_t)BB * HHD * SSQ * SSQ;    // (B,S,NP)  32K f32

    // d_ws: tiny header only (dtype flag + 512KB bitmask).
    int* flag = (int*)d_ws;
    u64* bitmask = (u64*)((char*)d_ws + 65536);           // (B*S,16) = 512KB

    // All large scratch lives INSIDE out1's 134MB, overwritten by maskwrite.
    char* SCR = (char*)out1;
    float* Qf32 = (float*)(SCR);                          // [0,8M)
    float* Kf32 = (float*)(SCR + (8ull << 20));           // [8M,16M)
    float* Vf32 = (float*)(SCR + (16ull << 20));          // [16M,24M)
    float* AO   = (float*)(SCR + (24ull << 20));          // [24M,32M)
    float* S3f  = (float*)(SCR + (32ull << 20));          // [32M,48M) all-batch scores

    detect_kernel<<<dim3(1), dim3(64), 0, stream>>>(query, flag);

    pattern_kernel<<<dim3(BB * SSQ), dim3(64), 0, stream>>>(
        query, pw1, pb1, pw2, pb2, pattern_bank, pattern_gate, flag, out2);

    // f32 Q/K/V projections (exact sequential-FMA-chain semantics)
    projf_kernel<<<dim3(DDM / 64, BB * SSQ / 64, 3), dim3(256), 0, stream>>>(
        query, key, value, wq, bq, wk, bk, wv, bv, flag, Qf32, Kf32, Vf32);

    // f32 scores, all batches in one launch
    scoresf_kernel<<<dim3(SSQ / 64, SSQ / 64, BB), dim3(256), 0, stream>>>(
        Qf32, Kf32, S3f);

    // top-204 per row, all batches, radix select (integer-exact)
    maskselect_kernel<<<dim3(SSQ, BB), dim3(256), 0, stream>>>(S3f, bitmask);

    // sparse attention: one block per (b,h,i) row
    attn_sparse_kernel<<<dim3(SSQ, HHD, BB), dim3(256), 0, stream>>>(
        Qf32, Kf32, Vf32, bitmask, AO);

    outproj_kernel<<<dim3(DDM / 64, BB * SSQ / 64), dim3(256), 0, stream>>>(
        AO, wo, bo, flag, out0);

    // LAST: expand bitmask into out1 (f32 mask), erasing all scratch
    maskwrite_kernel<<<dim3(BB * SSQ), dim3(256), 0, stream>>>(bitmask, out1);
}